// Round 6
// baseline (500.481 us; speedup 1.0000x reference)
//
#include <hip/hip_runtime.h>

#define N_NODES 50000
#define N_EDGES 800000
#define D 64
#define NUM_LAYERS 4
#define NUM_GRAPHS 128
#define N_ALL (2 * N_NODES)
#define E_ALL (2 * N_EDGES)
#define NB_SCAN ((N_ALL + 255) / 256)

// ---------- bf16 helpers (RNE pack, shift unpack) ----------
__device__ __forceinline__ unsigned f2bf(float f) {
    unsigned u = __float_as_uint(f);
    return (u + 0x7FFFu + ((u >> 16) & 1u)) >> 16;
}
__device__ __forceinline__ float bflo(unsigned p) { return __uint_as_float(p << 16); }
__device__ __forceinline__ float bfhi(unsigned p) { return __uint_as_float(p & 0xFFFF0000u); }
__device__ __forceinline__ void acc4(float* a, uint2 v) {
    a[0] += bflo(v.x); a[1] += bfhi(v.x);
    a[2] += bflo(v.y); a[3] += bfhi(v.y);
}
__device__ __forceinline__ void acc8(float* a, uint4 v) {
    a[0] += bflo(v.x); a[1] += bfhi(v.x);
    a[2] += bflo(v.y); a[3] += bfhi(v.y);
    a[4] += bflo(v.z); a[5] += bfhi(v.z);
    a[6] += bflo(v.w); a[7] += bfhi(v.w);
}

// ---------- combined CSR build over 100K-node space ----------
__global__ void hist2(const int* __restrict__ dR, const int* __restrict__ dX,
                      int* __restrict__ deg) {
    int e = blockIdx.x * 256 + threadIdx.x;
    if (e < N_EDGES) {
        atomicAdd(&deg[dR[e]], 1);
        atomicAdd(&deg[N_NODES + dX[e]], 1);
    }
}

__global__ void scan_partial(const int* __restrict__ deg, int* __restrict__ bsum) {
    __shared__ int s[256];
    int t = threadIdx.x;
    int idx = blockIdx.x * 256 + t;
    s[t] = (idx < N_ALL) ? deg[idx] : 0;
    __syncthreads();
    for (int off = 128; off > 0; off >>= 1) {
        if (t < off) s[t] += s[t + off];
        __syncthreads();
    }
    if (t == 0) bsum[blockIdx.x] = s[0];
}

__global__ void scan_bsums(int* __restrict__ bsum, int nb) {  // 512 threads
    __shared__ int s[512];
    int t = threadIdx.x;
    int v = (t < nb) ? bsum[t] : 0;
    s[t] = v;
    __syncthreads();
    for (int off = 1; off < 512; off <<= 1) {
        int tv = (t >= off) ? s[t - off] : 0;
        __syncthreads();
        s[t] += tv;
        __syncthreads();
    }
    if (t < nb) bsum[t] = s[t] - v;
}

__global__ void scan_write(const int* __restrict__ deg, const int* __restrict__ bsum,
                           int* __restrict__ rowptr, int* __restrict__ cursor) {
    __shared__ int s[256];
    int t = threadIdx.x;
    int idx = blockIdx.x * 256 + t;
    int v = (idx < N_ALL) ? deg[idx] : 0;
    s[t] = v;
    __syncthreads();
    for (int off = 1; off < 256; off <<= 1) {
        int tv = (t >= off) ? s[t - off] : 0;
        __syncthreads();
        s[t] += tv;
        __syncthreads();
    }
    if (idx < N_ALL) {
        int excl = s[t] - v + bsum[blockIdx.x];
        rowptr[idx] = excl;
        cursor[idx] = excl;
    }
    if (blockIdx.x == 0 && t == 0) rowptr[N_ALL] = E_ALL;
}

// Single-pass fill. col written via atomicExch: device-scope atomic lands at the
// memory-side coherence point as a 4B op -- no 64B partial-line write-back per store.
#define FILL_EPT 4
#define FILL_NS ((E_ALL + 256 * FILL_EPT - 1) / (256 * FILL_EPT))
__global__ __launch_bounds__(256) void fill_atomic(const int* __restrict__ sR,
                                                   const int* __restrict__ dR,
                                                   const int* __restrict__ sX,
                                                   const int* __restrict__ dX,
                                                   int* __restrict__ cursor,
                                                   int* __restrict__ col) {
    int base = blockIdx.x * (256 * FILL_EPT) + threadIdx.x;
#pragma unroll
    for (int k = 0; k < FILL_EPT; ++k) {
        int e = base + k * 256;
        if (e < E_ALL) {
            bool isR = (e < N_EDGES);
            int d = isR ? dR[e] : (N_NODES + dX[e - N_EDGES]);
            int s = isR ? sR[e] : sX[e - N_EDGES];
            int p = atomicAdd(&cursor[d], 1);
            atomicExch(&col[p], s);
        }
    }
}

// ---------- bf16 gather: out[i] = x[i] + sum_{e in row(i)} x[col[e]] ----------
// 8 lanes/node (uint4 = 8 bf16), 8 nodes/wave, 32 nodes/block. <=64 VGPR for 8 waves/EU.
__global__ __launch_bounds__(256, 8) void gather_bf16(const uint4* __restrict__ xb,
                                                      uint4* __restrict__ ob,
                                                      const int* __restrict__ rowptr,
                                                      const int* __restrict__ col) {
    int t = threadIdx.x;
    int grp = t >> 3, ln = t & 7;
    int node = blockIdx.x * 32 + grp;
    if (node >= N_NODES) return;
    int beg = rowptr[node], end = rowptr[node + 1];
    float a[8];
    {
        uint4 v = xb[(size_t)node * 8 + ln];
        a[0] = bflo(v.x); a[1] = bfhi(v.x); a[2] = bflo(v.y); a[3] = bfhi(v.y);
        a[4] = bflo(v.z); a[5] = bfhi(v.z); a[6] = bflo(v.w); a[7] = bfhi(v.w);
    }
    int e = beg;
    for (; e + 4 <= end; e += 4) {
        int s0 = col[e], s1 = col[e + 1], s2 = col[e + 2], s3 = col[e + 3];
        uint4 v0 = xb[(size_t)s0 * 8 + ln];
        uint4 v1 = xb[(size_t)s1 * 8 + ln];
        uint4 v2 = xb[(size_t)s2 * 8 + ln];
        uint4 v3 = xb[(size_t)s3 * 8 + ln];
        acc8(a, v0); acc8(a, v1); acc8(a, v2); acc8(a, v3);
    }
    for (; e < end; ++e) acc8(a, xb[(size_t)col[e] * 8 + ln]);
    uint4 o;
    o.x = f2bf(a[0]) | (f2bf(a[1]) << 16);
    o.y = f2bf(a[2]) | (f2bf(a[3]) << 16);
    o.z = f2bf(a[4]) | (f2bf(a[5]) << 16);
    o.w = f2bf(a[6]) | (f2bf(a[7]) << 16);
    ob[(size_t)node * 8 + ln] = o;
}

// ---------- fused: y = relu( (x + gather(x)) @ W^T + b ) ----------
// 16 nodes/block, 16 lanes/node, 4 fp32 accumulators/thread in both phases.
// Templated on input dtype: fp32 (layer 0, reads x_in directly) or bf16.
template <bool F32IN>
__global__ __launch_bounds__(256, 6) void gather_linear(const void* __restrict__ xv,
                                                        unsigned short* __restrict__ y,
                                                        const int* __restrict__ rowptr,
                                                        const int* __restrict__ col,
                                                        const float* __restrict__ W,
                                                        const float* __restrict__ b) {
    __shared__ float Wl[64 * 65];   // stride 65: Wl[o*65+k] reads conflict-free
    __shared__ float hl[16 * 64];
    int t = threadIdx.x;
#pragma unroll
    for (int i = 0; i < 16; ++i) {  // coalesced W stage
        int idx = i * 256 + t;
        Wl[(idx >> 6) * 65 + (idx & 63)] = W[idx];
    }
    int grp = t >> 4, ln = t & 15;
    int node = blockIdx.x * 16 + grp;       // grid exactly covers 50000
    int beg = rowptr[node], end = rowptr[node + 1];
    float a[4];
    if (F32IN) {
        const float4* xf = (const float4*)xv;
        float4 v = xf[(size_t)node * 16 + ln];
        a[0] = v.x; a[1] = v.y; a[2] = v.z; a[3] = v.w;
        int e = beg;
        for (; e + 4 <= end; e += 4) {
            int s0 = col[e], s1 = col[e + 1], s2 = col[e + 2], s3 = col[e + 3];
            float4 v0 = xf[(size_t)s0 * 16 + ln];
            float4 v1 = xf[(size_t)s1 * 16 + ln];
            float4 v2 = xf[(size_t)s2 * 16 + ln];
            float4 v3 = xf[(size_t)s3 * 16 + ln];
            a[0] += v0.x + v1.x + v2.x + v3.x;
            a[1] += v0.y + v1.y + v2.y + v3.y;
            a[2] += v0.z + v1.z + v2.z + v3.z;
            a[3] += v0.w + v1.w + v2.w + v3.w;
        }
        for (; e < end; ++e) {
            float4 v4 = xf[(size_t)col[e] * 16 + ln];
            a[0] += v4.x; a[1] += v4.y; a[2] += v4.z; a[3] += v4.w;
        }
    } else {
        const uint2* xb = (const uint2*)xv;
        uint2 v = xb[(size_t)node * 16 + ln];
        a[0] = bflo(v.x); a[1] = bfhi(v.x); a[2] = bflo(v.y); a[3] = bfhi(v.y);
        int e = beg;
        for (; e + 4 <= end; e += 4) {
            int s0 = col[e], s1 = col[e + 1], s2 = col[e + 2], s3 = col[e + 3];
            uint2 v0 = xb[(size_t)s0 * 16 + ln];
            uint2 v1 = xb[(size_t)s1 * 16 + ln];
            uint2 v2 = xb[(size_t)s2 * 16 + ln];
            uint2 v3 = xb[(size_t)s3 * 16 + ln];
            acc4(a, v0); acc4(a, v1); acc4(a, v2); acc4(a, v3);
        }
        for (; e < end; ++e) acc4(a, xb[(size_t)col[e] * 16 + ln]);
    }
    *((float4*)(hl + grp * 64 + ln * 4)) = make_float4(a[0], a[1], a[2], a[3]);
    __syncthreads();

    // GEMM: 16 nodes x 64 outs, 4 per thread; hl reads are wave-broadcast.
    int o = t & 63, nb = t >> 6;
    float bo = b[o];
    float a0 = bo, a1 = bo, a2 = bo, a3 = bo;
#pragma unroll
    for (int k = 0; k < 64; ++k) {
        float w = Wl[o * 65 + k];
        a0 += hl[(nb     ) * 64 + k] * w;
        a1 += hl[(nb +  4) * 64 + k] * w;
        a2 += hl[(nb +  8) * 64 + k] * w;
        a3 += hl[(nb + 12) * 64 + k] * w;
    }
    size_t base = (size_t)blockIdx.x * 16;
    y[(base + nb     ) * 64 + o] = (unsigned short)f2bf(fmaxf(a0, 0.0f));
    y[(base + nb +  4) * 64 + o] = (unsigned short)f2bf(fmaxf(a1, 0.0f));
    y[(base + nb +  8) * 64 + o] = (unsigned short)f2bf(fmaxf(a2, 0.0f));
    y[(base + nb + 12) * 64 + o] = (unsigned short)f2bf(fmaxf(a3, 0.0f));
}

// ---------- pool: batch sorted -> contiguous segments ----------
__device__ __forceinline__ int lower_bound_dev(const int* __restrict__ a, int n, int v) {
    int lo = 0, hi = n;
    while (lo < hi) { int mid = (lo + hi) >> 1; if (a[mid] < v) lo = mid + 1; else hi = mid; }
    return lo;
}

__global__ __launch_bounds__(256) void pool_seg_bf16(const unsigned short* __restrict__ xb,
                                                     const int* __restrict__ batch,
                                                     float* __restrict__ out) {
    int g = blockIdx.x;
    int lo = lower_bound_dev(batch, N_NODES, g);
    int hi = lower_bound_dev(batch, N_NODES, g + 1);
    int lane = threadIdx.x & 63;
    int sub = threadIdx.x >> 6;
    float acc = 0.0f;
    for (int n = lo + sub; n < hi; n += 4)
        acc += __uint_as_float(((unsigned)xb[(size_t)n * 64 + lane]) << 16);
    __shared__ float red[256];
    red[threadIdx.x] = acc;
    __syncthreads();
    if (sub == 0)
        out[(size_t)g * D + lane] = red[lane] + red[64 + lane] + red[128 + lane] + red[192 + lane];
}

// ---------- host ----------
extern "C" void kernel_launch(void* const* d_in, const int* in_sizes, int n_in,
                              void* d_out, int out_size, void* d_ws, size_t ws_size,
                              hipStream_t stream) {
    const float* x_in  = (const float*)d_in[0];
    const int*   ei    = (const int*)d_in[1];
    const int*   eei   = (const int*)d_in[2];
    const int*   batch = (const int*)d_in[3];
    const float* Ws    = (const float*)d_in[4];
    const float* bs    = (const float*)d_in[5];
    float* out = (float*)d_out;

    unsigned short* A = (unsigned short*)d_ws;          // y (bf16)
    unsigned short* B = A + (size_t)N_NODES * D;        // x' (bf16)
    int* p = (int*)(B + (size_t)N_NODES * D);
    int* rowptr = p;   p += N_ALL + 1;
    int* cursor = p;   p += N_ALL;
    int* colAll = p;   p += E_ALL;
    int* deg    = p;   p += N_ALL;
    int* bsum   = p;   p += 512;

    const int* e_src = ei;
    const int* e_dst = ei + N_EDGES;
    const int* x_src = eei;
    const int* x_dst = eei + N_EDGES;

    dim3 blk(256);

    // combined CSR build
    hipMemsetAsync(deg, 0, N_ALL * sizeof(int), stream);
    hist2<<<(N_EDGES + 255) / 256, blk, 0, stream>>>(e_dst, x_dst, deg);
    scan_partial<<<NB_SCAN, blk, 0, stream>>>(deg, bsum);
    scan_bsums<<<1, 512, 0, stream>>>(bsum, NB_SCAN);
    scan_write<<<NB_SCAN, blk, 0, stream>>>(deg, bsum, rowptr, cursor);
    fill_atomic<<<FILL_NS, blk, 0, stream>>>(e_src, e_dst, x_src, x_dst, cursor, colAll);

    const int lgrid = N_NODES / 16;            // 3125, exact
    const int ggrid = (N_NODES + 31) / 32;     // 1563

    // layer 0: fp32 input
    gather_linear<true><<<lgrid, blk, 0, stream>>>((const void*)x_in, A,
                                                   rowptr, colAll, Ws, bs);
    gather_bf16<<<ggrid, blk, 0, stream>>>((const uint4*)A, (uint4*)B,
                                           rowptr + N_NODES, colAll);
    // layers 1..3: bf16 input
    for (int i = 1; i < NUM_LAYERS; ++i) {
        gather_linear<false><<<lgrid, blk, 0, stream>>>((const void*)B, A,
                                                        rowptr, colAll,
                                                        Ws + (size_t)i * D * D,
                                                        bs + (size_t)i * D);
        gather_bf16<<<ggrid, blk, 0, stream>>>((const uint4*)A, (uint4*)B,
                                               rowptr + N_NODES, colAll);
    }

    pool_seg_bf16<<<NUM_GRAPHS, blk, 0, stream>>>(B, batch, out);
}

// Round 7
// 419.612 us; speedup vs baseline: 1.1927x; 1.1927x over previous
//
#include <hip/hip_runtime.h>

#define N_NODES 50000
#define N_EDGES 800000
#define D 64
#define NUM_LAYERS 4
#define NUM_GRAPHS 128
#define N_ALL (2 * N_NODES)
#define E_ALL (2 * N_EDGES)
#define NB_SCAN ((N_ALL + 255) / 256)

// ---------- bf16 helpers (RNE pack, shift unpack) ----------
__device__ __forceinline__ unsigned f2bf(float f) {
    unsigned u = __float_as_uint(f);
    return (u + 0x7FFFu + ((u >> 16) & 1u)) >> 16;
}
__device__ __forceinline__ float bflo(unsigned p) { return __uint_as_float(p << 16); }
__device__ __forceinline__ float bfhi(unsigned p) { return __uint_as_float(p & 0xFFFF0000u); }
__device__ __forceinline__ void acc8(float* a, uint4 v) {
    a[0] += bflo(v.x); a[1] += bfhi(v.x);
    a[2] += bflo(v.y); a[3] += bfhi(v.y);
    a[4] += bflo(v.z); a[5] += bfhi(v.z);
    a[6] += bflo(v.w); a[7] += bfhi(v.w);
}

// ---------- combined CSR build over 100K-node space ----------
__global__ void hist2(const int* __restrict__ dR, const int* __restrict__ dX,
                      int* __restrict__ deg) {
    int e = blockIdx.x * 256 + threadIdx.x;
    if (e < N_EDGES) {
        atomicAdd(&deg[dR[e]], 1);
        atomicAdd(&deg[N_NODES + dX[e]], 1);
    }
}

__global__ void scan_partial(const int* __restrict__ deg, int* __restrict__ bsum) {
    __shared__ int s[256];
    int t = threadIdx.x;
    int idx = blockIdx.x * 256 + t;
    s[t] = (idx < N_ALL) ? deg[idx] : 0;
    __syncthreads();
    for (int off = 128; off > 0; off >>= 1) {
        if (t < off) s[t] += s[t + off];
        __syncthreads();
    }
    if (t == 0) bsum[blockIdx.x] = s[0];
}

__global__ void scan_bsums(int* __restrict__ bsum, int nb) {  // 512 threads
    __shared__ int s[512];
    int t = threadIdx.x;
    int v = (t < nb) ? bsum[t] : 0;
    s[t] = v;
    __syncthreads();
    for (int off = 1; off < 512; off <<= 1) {
        int tv = (t >= off) ? s[t - off] : 0;
        __syncthreads();
        s[t] += tv;
        __syncthreads();
    }
    if (t < nb) bsum[t] = s[t] - v;
}

__global__ void scan_write(const int* __restrict__ deg, const int* __restrict__ bsum,
                           int* __restrict__ rowptr, int* __restrict__ cursor) {
    __shared__ int s[256];
    int t = threadIdx.x;
    int idx = blockIdx.x * 256 + t;
    int v = (idx < N_ALL) ? deg[idx] : 0;
    s[t] = v;
    __syncthreads();
    for (int off = 1; off < 256; off <<= 1) {
        int tv = (t >= off) ? s[t - off] : 0;
        __syncthreads();
        s[t] += tv;
        __syncthreads();
    }
    if (idx < N_ALL) {
        int excl = s[t] - v + bsum[blockIdx.x];
        rowptr[idx] = excl;
        cursor[idx] = excl;
    }
    if (blockIdx.x == 0 && t == 0) rowptr[N_ALL] = E_ALL;
}

// XCD-phased fill (R5 version, measured 71us): phase r = blockIdx%8 handles
// dst range [r*12500,(r+1)*12500) so col windows mostly stay in one XCD's L2.
#define FILL_EPT 4
#define FILL_NS ((E_ALL + 256 * FILL_EPT - 1) / (256 * FILL_EPT))
#define NPP (N_ALL / 8)
__global__ __launch_bounds__(256) void fill_phased(const int* __restrict__ sR,
                                                   const int* __restrict__ dR,
                                                   const int* __restrict__ sX,
                                                   const int* __restrict__ dX,
                                                   int* __restrict__ cursor,
                                                   int* __restrict__ col) {
    int phase = blockIdx.x & 7;
    int slice = blockIdx.x >> 3;
    int lo = phase * NPP, hi = lo + NPP;
    int base = slice * (256 * FILL_EPT) + threadIdx.x;
#pragma unroll
    for (int k = 0; k < FILL_EPT; ++k) {
        int e = base + k * 256;
        if (e < E_ALL) {
            bool isR = (e < N_EDGES);
            int d = isR ? dR[e] : (N_NODES + dX[e - N_EDGES]);
            if (d >= lo && d < hi) {
                int s = isR ? sR[e] : sX[e - N_EDGES];
                int p = atomicAdd(&cursor[d], 1);
                col[p] = s;
            }
        }
    }
}

// ---------- split-edge bf16 gather: out[i] = x[i] + sum_{e in row(i)} x[col[e]] ----------
// 16 lanes per node; two 8-lane sub-teams split the edge list (even/odd index),
// each sub-team reads full 128B rows (uint4/lane). Merge via shfl_xor(8).
// Doubles independent load chains per node, halves chain depth + imbalance.
__global__ __launch_bounds__(256, 8) void gather_bf16(const uint4* __restrict__ xb,
                                                      uint4* __restrict__ ob,
                                                      const int* __restrict__ rowptr,
                                                      const int* __restrict__ col) {
    int t = threadIdx.x;
    int grp = t >> 4;                 // node within block (16 nodes/block)
    int half = (t >> 3) & 1;          // sub-team
    int ln8 = t & 7;                  // uint4 slot within row
    int node = blockIdx.x * 16 + grp; // grid exactly covers 50000
    int beg = rowptr[node], end = rowptr[node + 1];
    int cnt = end - beg;
    int ch = (cnt - half + 1) >> 1;   // edges for this half
    const int* cp = col + beg + half; // stride-2 walk
    float a[8];
    if (half == 0) {
        uint4 v = xb[(size_t)node * 8 + ln8];
        a[0] = bflo(v.x); a[1] = bfhi(v.x); a[2] = bflo(v.y); a[3] = bfhi(v.y);
        a[4] = bflo(v.z); a[5] = bfhi(v.z); a[6] = bflo(v.w); a[7] = bfhi(v.w);
    } else {
#pragma unroll
        for (int i = 0; i < 8; ++i) a[i] = 0.0f;
    }
    int i = 0;
    for (; i + 4 <= ch; i += 4) {
        int s0 = cp[2 * i], s1 = cp[2 * i + 2], s2 = cp[2 * i + 4], s3 = cp[2 * i + 6];
        uint4 v0 = xb[(size_t)s0 * 8 + ln8];
        uint4 v1 = xb[(size_t)s1 * 8 + ln8];
        uint4 v2 = xb[(size_t)s2 * 8 + ln8];
        uint4 v3 = xb[(size_t)s3 * 8 + ln8];
        acc8(a, v0); acc8(a, v1); acc8(a, v2); acc8(a, v3);
    }
    for (; i < ch; ++i) acc8(a, xb[(size_t)cp[2 * i] * 8 + ln8]);
#pragma unroll
    for (int j = 0; j < 8; ++j) a[j] += __shfl_xor(a[j], 8);
    if (half == 0) {
        uint4 o;
        o.x = f2bf(a[0]) | (f2bf(a[1]) << 16);
        o.y = f2bf(a[2]) | (f2bf(a[3]) << 16);
        o.z = f2bf(a[4]) | (f2bf(a[5]) << 16);
        o.w = f2bf(a[6]) | (f2bf(a[7]) << 16);
        ob[(size_t)node * 8 + ln8] = o;
    }
}

// ---------- fused: y = relu( (x + gather(x)) @ W^T + b ) ----------
// bf16 path uses the same split-edge structure; fp32 path (layer 0) keeps the
// simple 16-lane float4 walk. 16 nodes/block.
template <bool F32IN>
__global__ __launch_bounds__(256, 4) void gather_linear(const void* __restrict__ xv,
                                                        unsigned short* __restrict__ y,
                                                        const int* __restrict__ rowptr,
                                                        const int* __restrict__ col,
                                                        const float* __restrict__ W,
                                                        const float* __restrict__ b) {
    __shared__ float Wl[64 * 65];   // stride 65: Wl[o*65+k] reads conflict-free
    __shared__ float hl[16 * 64];
    int t = threadIdx.x;
#pragma unroll
    for (int i = 0; i < 16; ++i) {  // coalesced W stage
        int idx = i * 256 + t;
        Wl[(idx >> 6) * 65 + (idx & 63)] = W[idx];
    }
    int grp = t >> 4;
    int node = blockIdx.x * 16 + grp;       // grid exactly covers 50000
    int beg = rowptr[node], end = rowptr[node + 1];
    if (F32IN) {
        int ln = t & 15;
        const float4* xf = (const float4*)xv;
        float4 v = xf[(size_t)node * 16 + ln];
        float a0 = v.x, a1 = v.y, a2 = v.z, a3 = v.w;
        int e = beg;
        for (; e + 4 <= end; e += 4) {
            int s0 = col[e], s1 = col[e + 1], s2 = col[e + 2], s3 = col[e + 3];
            float4 v0 = xf[(size_t)s0 * 16 + ln];
            float4 v1 = xf[(size_t)s1 * 16 + ln];
            float4 v2 = xf[(size_t)s2 * 16 + ln];
            float4 v3 = xf[(size_t)s3 * 16 + ln];
            a0 += v0.x + v1.x + v2.x + v3.x;
            a1 += v0.y + v1.y + v2.y + v3.y;
            a2 += v0.z + v1.z + v2.z + v3.z;
            a3 += v0.w + v1.w + v2.w + v3.w;
        }
        for (; e < end; ++e) {
            float4 v4 = xf[(size_t)col[e] * 16 + ln];
            a0 += v4.x; a1 += v4.y; a2 += v4.z; a3 += v4.w;
        }
        *((float4*)(hl + grp * 64 + ln * 4)) = make_float4(a0, a1, a2, a3);
    } else {
        int half = (t >> 3) & 1;
        int ln8 = t & 7;
        const uint4* xb = (const uint4*)xv;
        int cnt = end - beg;
        int ch = (cnt - half + 1) >> 1;
        const int* cp = col + beg + half;
        float a[8];
        if (half == 0) {
            uint4 v = xb[(size_t)node * 8 + ln8];
            a[0] = bflo(v.x); a[1] = bfhi(v.x); a[2] = bflo(v.y); a[3] = bfhi(v.y);
            a[4] = bflo(v.z); a[5] = bfhi(v.z); a[6] = bflo(v.w); a[7] = bfhi(v.w);
        } else {
#pragma unroll
            for (int i = 0; i < 8; ++i) a[i] = 0.0f;
        }
        int i = 0;
        for (; i + 4 <= ch; i += 4) {
            int s0 = cp[2 * i], s1 = cp[2 * i + 2], s2 = cp[2 * i + 4], s3 = cp[2 * i + 6];
            uint4 v0 = xb[(size_t)s0 * 8 + ln8];
            uint4 v1 = xb[(size_t)s1 * 8 + ln8];
            uint4 v2 = xb[(size_t)s2 * 8 + ln8];
            uint4 v3 = xb[(size_t)s3 * 8 + ln8];
            acc8(a, v0); acc8(a, v1); acc8(a, v2); acc8(a, v3);
        }
        for (; i < ch; ++i) acc8(a, xb[(size_t)cp[2 * i] * 8 + ln8]);
#pragma unroll
        for (int j = 0; j < 8; ++j) a[j] += __shfl_xor(a[j], 8);
        if (half == 0) {
            float4* hp = (float4*)(hl + grp * 64 + ln8 * 8);
            hp[0] = make_float4(a[0], a[1], a[2], a[3]);
            hp[1] = make_float4(a[4], a[5], a[6], a[7]);
        }
    }
    __syncthreads();

    // GEMM: 16 nodes x 64 outs, 4 per thread; hl reads are wave-broadcast.
    int o = t & 63, nb = t >> 6;
    float bo = b[o];
    float a0 = bo, a1 = bo, a2 = bo, a3 = bo;
#pragma unroll
    for (int k = 0; k < 64; ++k) {
        float w = Wl[o * 65 + k];
        a0 += hl[(nb     ) * 64 + k] * w;
        a1 += hl[(nb +  4) * 64 + k] * w;
        a2 += hl[(nb +  8) * 64 + k] * w;
        a3 += hl[(nb + 12) * 64 + k] * w;
    }
    size_t base = (size_t)blockIdx.x * 16;
    y[(base + nb     ) * 64 + o] = (unsigned short)f2bf(fmaxf(a0, 0.0f));
    y[(base + nb +  4) * 64 + o] = (unsigned short)f2bf(fmaxf(a1, 0.0f));
    y[(base + nb +  8) * 64 + o] = (unsigned short)f2bf(fmaxf(a2, 0.0f));
    y[(base + nb + 12) * 64 + o] = (unsigned short)f2bf(fmaxf(a3, 0.0f));
}

// ---------- pool: batch sorted -> contiguous segments ----------
__device__ __forceinline__ int lower_bound_dev(const int* __restrict__ a, int n, int v) {
    int lo = 0, hi = n;
    while (lo < hi) { int mid = (lo + hi) >> 1; if (a[mid] < v) lo = mid + 1; else hi = mid; }
    return lo;
}

__global__ __launch_bounds__(256) void pool_seg_bf16(const unsigned short* __restrict__ xb,
                                                     const int* __restrict__ batch,
                                                     float* __restrict__ out) {
    int g = blockIdx.x;
    int lo = lower_bound_dev(batch, N_NODES, g);
    int hi = lower_bound_dev(batch, N_NODES, g + 1);
    int lane = threadIdx.x & 63;
    int sub = threadIdx.x >> 6;
    float acc = 0.0f;
    for (int n = lo + sub; n < hi; n += 4)
        acc += __uint_as_float(((unsigned)xb[(size_t)n * 64 + lane]) << 16);
    __shared__ float red[256];
    red[threadIdx.x] = acc;
    __syncthreads();
    if (sub == 0)
        out[(size_t)g * D + lane] = red[lane] + red[64 + lane] + red[128 + lane] + red[192 + lane];
}

// ---------- host ----------
extern "C" void kernel_launch(void* const* d_in, const int* in_sizes, int n_in,
                              void* d_out, int out_size, void* d_ws, size_t ws_size,
                              hipStream_t stream) {
    const float* x_in  = (const float*)d_in[0];
    const int*   ei    = (const int*)d_in[1];
    const int*   eei   = (const int*)d_in[2];
    const int*   batch = (const int*)d_in[3];
    const float* Ws    = (const float*)d_in[4];
    const float* bs    = (const float*)d_in[5];
    float* out = (float*)d_out;

    unsigned short* A = (unsigned short*)d_ws;          // y (bf16)
    unsigned short* B = A + (size_t)N_NODES * D;        // x' (bf16)
    int* p = (int*)(B + (size_t)N_NODES * D);
    int* rowptr = p;   p += N_ALL + 1;
    int* cursor = p;   p += N_ALL;
    int* colAll = p;   p += E_ALL;
    int* deg    = p;   p += N_ALL;
    int* bsum   = p;   p += 512;

    const int* e_src = ei;
    const int* e_dst = ei + N_EDGES;
    const int* x_src = eei;
    const int* x_dst = eei + N_EDGES;

    dim3 blk(256);

    // combined CSR build
    hipMemsetAsync(deg, 0, N_ALL * sizeof(int), stream);
    hist2<<<(N_EDGES + 255) / 256, blk, 0, stream>>>(e_dst, x_dst, deg);
    scan_partial<<<NB_SCAN, blk, 0, stream>>>(deg, bsum);
    scan_bsums<<<1, 512, 0, stream>>>(bsum, NB_SCAN);
    scan_write<<<NB_SCAN, blk, 0, stream>>>(deg, bsum, rowptr, cursor);
    fill_phased<<<8 * FILL_NS, blk, 0, stream>>>(e_src, e_dst, x_src, x_dst, cursor, colAll);

    const int lgrid = N_NODES / 16;            // 3125, exact (both kernels)

    // layer 0: fp32 input
    gather_linear<true><<<lgrid, blk, 0, stream>>>((const void*)x_in, A,
                                                   rowptr, colAll, Ws, bs);
    gather_bf16<<<lgrid, blk, 0, stream>>>((const uint4*)A, (uint4*)B,
                                           rowptr + N_NODES, colAll);
    // layers 1..3: bf16 input
    for (int i = 1; i < NUM_LAYERS; ++i) {
        gather_linear<false><<<lgrid, blk, 0, stream>>>((const void*)B, A,
                                                        rowptr, colAll,
                                                        Ws + (size_t)i * D * D,
                                                        bs + (size_t)i * D);
        gather_bf16<<<lgrid, blk, 0, stream>>>((const uint4*)A, (uint4*)B,
                                               rowptr + N_NODES, colAll);
    }

    pool_seg_bf16<<<NUM_GRAPHS, blk, 0, stream>>>(B, batch, out);
}